// Round 7
// baseline (551.872 us; speedup 1.0000x reference)
//
#include <hip/hip_runtime.h>
#include <math.h>

#define NPB 4096
#define BB 2
#define NN (NPB*BB)          // 8192
#define DIM 64
#define KK 5
#define NKR (NPB*KK)         // 20480
#define ET (BB*NKR)          // 40960 edges
#define SPLITS 16
#define RPS (NPB/SPLITS)     // 256 rows per split
#define NT8 (RPS/32)         // 8 mfma row-tiles per split

typedef __attribute__((ext_vector_type(8))) __bf16 bf16x8;
typedef __attribute__((ext_vector_type(16))) float f32x16;

__device__ __forceinline__ float clip_exp(const float* tptr) {
    return expf(fminf(fmaxf(tptr[0], -5.0f), 5.0f));
}

__device__ __forceinline__ unsigned enc_f(float f) {
    unsigned u = __float_as_uint(f);
    return (u & 0x80000000u) ? ~u : (u | 0x80000000u);
}
__device__ __forceinline__ float dec_f(unsigned e) {
    unsigned u = (e & 0x80000000u) ? (e ^ 0x80000000u) : ~e;
    return __uint_as_float(u);
}

// RNE float -> bf16 bits (finite inputs only)
__device__ __forceinline__ unsigned short f2bf(float f) {
    unsigned u = __float_as_uint(f);
    unsigned r = u + 0x7FFFu + ((u >> 16) & 1u);
    return (unsigned short)(r >> 16);
}

// top-N ascending insert. LEX=false: strict-less (stable when candidates are
// scanned in ascending index order). LEX=true: (d, idx) lexicographic (merge
// in arbitrary order). All indices compile-time constant after unroll.
template<int NK, bool LEX>
__device__ __forceinline__ void insN(float (&d)[NK], int (&ix)[NK], float dd, int ii) {
    bool c[NK];
#pragma unroll
    for (int m = 0; m < NK; ++m)
        c[m] = LEX ? (dd < d[m] || (dd == d[m] && ii < ix[m])) : (dd < d[m]);
    if (c[NK - 1]) {
#pragma unroll
        for (int m = NK - 1; m > 0; --m) {
            d[m]  = c[m - 1] ? d[m - 1]  : (c[m] ? dd : d[m]);
            ix[m] = c[m - 1] ? ix[m - 1] : (c[m] ? ii : ix[m]);
        }
        if (c[0]) { d[0] = dd; ix[0] = ii; }
    }
}

// ---------------- pre_fc: Y = leaky_relu(X[8192,32] @ W[32,64] + b, 0.1)
__global__ __launch_bounds__(256) void k_prefc(const float* __restrict__ X,
        const float* __restrict__ W, const float* __restrict__ bias,
        float* __restrict__ Y) {
    int row = blockIdx.x * 4 + (threadIdx.x >> 6);
    int c = threadIdx.x & 63;
    const float* xr = X + (size_t)row * 32;
    float acc = bias[c];
#pragma unroll
    for (int d = 0; d < 32; ++d) acc = fmaf(xr[d], W[d * 64 + c], acc);
    Y[(size_t)row * 64 + c] = acc > 0.f ? acc : 0.1f * acc;
}

// ---------------- embed: Y = X1@W[0:64] (+ X2@W[64:128]) + b
// also emits bf16 hi/lo split of Y and row sq-norms
__global__ __launch_bounds__(256) void k_embed(const float* __restrict__ X1,
        const float* __restrict__ X2, const float* __restrict__ W,
        const float* __restrict__ bias, float* __restrict__ Y,
        float* __restrict__ sqout, unsigned short* __restrict__ GH,
        unsigned short* __restrict__ GL) {
    int row = blockIdx.x * 4 + (threadIdx.x >> 6);
    int c = threadIdx.x & 63;
    float acc = bias[c];
    const float* x1r = X1 + (size_t)row * DIM;
#pragma unroll 16
    for (int d = 0; d < DIM; ++d) acc = fmaf(x1r[d], W[d * DIM + c], acc);
    if (X2) {
        const float* x2r = X2 + (size_t)row * DIM;
#pragma unroll 16
        for (int d = 0; d < DIM; ++d) acc = fmaf(x2r[d], W[(DIM + d) * DIM + c], acc);
    }
    size_t idx = (size_t)row * DIM + c;
    Y[idx] = acc;
    unsigned short h = f2bf(acc);
    float hf = __uint_as_float((unsigned)h << 16);
    GH[idx] = h;
    GL[idx] = f2bf(acc - hf);
    float s = acc * acc;
#pragma unroll
    for (int off = 32; off; off >>= 1) s += __shfl_xor(s, off, 64);
    if (c == 0) sqout[row] = s;
}

// ---------------- P/Q for linearized EdgeConv:
// P = xf @ (W[0:64]-W[64:128]) + bias ; Q = xf @ W[64:128]
__global__ __launch_bounds__(256) void k_pq(const float* __restrict__ xf,
        const float* __restrict__ W, const float* __restrict__ bias,
        float* __restrict__ P, float* __restrict__ Q) {
    int row = blockIdx.x * 4 + (threadIdx.x >> 6);
    int c = threadIdx.x & 63;
    const float* xr = xf + (size_t)row * DIM;
    float ap = bias[c], aq = 0.f;
#pragma unroll 16
    for (int d = 0; d < DIM; ++d) {
        float xv = xr[d];
        float w1 = W[(DIM + d) * DIM + c];
        aq = fmaf(xv, w1, aq);
        ap = fmaf(xv, W[d * DIM + c] - w1, ap);
    }
    P[(size_t)row * DIM + c] = ap;
    Q[(size_t)row * DIM + c] = aq;
}

// ---------------- knn via MFMA: distance GEMM on split-bf16, approx top-8
// Grid: (NPB/128, BB, SPLITS), 256 threads = 4 waves; wave w owns cols
// [bx*128+32w, +32), rows [rs*RPS, +RPS). No LDS; frags straight from L2.
__global__ __launch_bounds__(256, 3) void k_knn_mfma(
        const unsigned short* __restrict__ GH, const unsigned short* __restrict__ GL,
        const float* __restrict__ sq, const float* __restrict__ tptr,
        float* __restrict__ pd, int* __restrict__ pi) {
    const int b_ = blockIdx.y, rs = blockIdx.z;
    const int w = threadIdx.x >> 6, lane = threadIdx.x & 63;
    const int half = lane >> 5, l31 = lane & 31;
    const int col = blockIdx.x * 128 + w * 32 + l31;
    const unsigned short* GHb = GH + (size_t)b_ * NPB * DIM;
    const unsigned short* GLb = GL + (size_t)b_ * NPB * DIM;
    const float* sqb = sq + (size_t)b_ * NPB;
    const float t = clip_exp(tptr);

    // B frags: col = lane&31, k = ks*16 + half*8 + e  (16B-aligned loads)
    bf16x8 Bh[4], Bl[4];
    {
        const size_t bro = (size_t)col * DIM + half * 8;
#pragma unroll
        for (int ks = 0; ks < 4; ++ks) {
            Bh[ks] = *(const bf16x8*)&GHb[bro + ks * 16];
            Bl[ks] = *(const bf16x8*)&GLb[bro + ks * 16];
        }
    }
    const float sj = sqb[col];

    float td[8]; int ti[8];
#pragma unroll
    for (int m = 0; m < 8; ++m) { td[m] = INFINITY; ti[m] = 0x7FFFFFFF; }

    const int r0 = rs * RPS;
    for (int tb = 0; tb < NT8; ++tb) {
        const int rbase = r0 + tb * 32;
        const size_t aro = (size_t)(rbase + l31) * DIM + half * 8;
        bf16x8 Ah[4], Al[4];
#pragma unroll
        for (int ks = 0; ks < 4; ++ks) {
            Ah[ks] = *(const bf16x8*)&GHb[aro + ks * 16];
            Al[ks] = *(const bf16x8*)&GLb[aro + ks * 16];
        }
        float st = sqb[rbase + l31];
        f32x16 acc = {0,0,0,0,0,0,0,0,0,0,0,0,0,0,0,0};
#pragma unroll
        for (int ks = 0; ks < 4; ++ks) {
            acc = __builtin_amdgcn_mfma_f32_32x32x16_bf16(Ah[ks], Bh[ks], acc, 0, 0, 0);
            acc = __builtin_amdgcn_mfma_f32_32x32x16_bf16(Ah[ks], Bl[ks], acc, 0, 0, 0);
            acc = __builtin_amdgcn_mfma_f32_32x32x16_bf16(Al[ks], Bh[ks], acc, 0, 0, 0);
        }
        // C: col=lane&31, row_in_tile = (reg&3)+8*(reg>>2)+4*half (ascending in reg)
#pragma unroll
        for (int reg = 0; reg < 16; ++reg) {
            const int rit = (reg & 3) + 8 * (reg >> 2) + 4 * half;
            float si = __shfl(st, rit, 32);
            float md = fmaxf(si + sj - 2.0f * acc[reg], 0.0f) * t;
            insN<8, false>(td, ti, md, rbase + rit);
        }
    }
    // merge the two halves (same col, disjoint row sets) lexicographically
    {
        float od[8]; int oi[8];
#pragma unroll
        for (int m = 0; m < 8; ++m) {
            od[m] = __shfl_xor(td[m], 32, 64);
            oi[m] = __shfl_xor(ti[m], 32, 64);
        }
#pragma unroll
        for (int m = 0; m < 8; ++m) insN<8, true>(td, ti, od[m], oi[m]);
    }
    if (half == 0) {
        size_t base = (((size_t)(b_ * SPLITS + rs)) * NPB + col) * 8;
#pragma unroll
        for (int m = 0; m < 8; ++m) { pd[base + m] = td[m]; pi[base + m] = ti[m]; }
    }
}

// merge SPLITS partial top-8 lists -> global approx top-8 indices per column
__global__ __launch_bounds__(256) void k_knnmerge8(const float* __restrict__ pd,
        const int* __restrict__ pi, int* __restrict__ c8) {
    int q = blockIdx.x * 256 + threadIdx.x;   // over BB*NPB
    int b_ = q >> 12, j = q & (NPB - 1);
    float td[8]; int ti[8];
#pragma unroll
    for (int m = 0; m < 8; ++m) { td[m] = INFINITY; ti[m] = 0x7FFFFFFF; }
    for (int rs = 0; rs < SPLITS; ++rs) {
        size_t base = (((size_t)(b_ * SPLITS + rs)) * NPB + j) * 8;
#pragma unroll
        for (int m = 0; m < 8; ++m) insN<8, true>(td, ti, pd[base + m], pi[base + m]);
    }
    int* o = c8 + (size_t)q * 8;
#pragma unroll
    for (int m = 0; m < 8; ++m) o[m] = ti[m];
}

// exact fp32 re-ranking of the 8 candidates -> stable top-5 (matches ref path)
__global__ __launch_bounds__(256) void k_refine(const float* __restrict__ ge,
        const float* __restrict__ sq, const int* __restrict__ c8,
        const float* __restrict__ tptr, int* __restrict__ idxout) {
    int q = blockIdx.x * 256 + threadIdx.x;   // over BB*NPB
    int b_ = q >> 12, j = q & (NPB - 1);
    const float* geb = ge + (size_t)b_ * NPB * DIM;
    const float* sqb = sq + (size_t)b_ * NPB;
    float t = clip_exp(tptr);
    float gj[DIM];
#pragma unroll
    for (int d = 0; d < DIM; ++d) gj[d] = geb[(size_t)j * DIM + d];
    float sjv = sqb[j];
    float td[KK]; int ti[KK];
#pragma unroll
    for (int m = 0; m < KK; ++m) { td[m] = INFINITY; ti[m] = 0x7FFFFFFF; }
    const int* cc = c8 + (size_t)q * 8;
#pragma unroll
    for (int m = 0; m < 8; ++m) {
        int i = cc[m];
        const float* gi = geb + (size_t)i * DIM;
        float dot = 0.f;
#pragma unroll 16
        for (int d = 0; d < DIM; ++d) dot = fmaf(gi[d], gj[d], dot);
        float md = fmaxf(sqb[i] + sjv - 2.0f * dot, 0.0f) * t;
        insN<KK, true>(td, ti, md, i);
    }
    int* o = idxout + (size_t)q * KK;
#pragma unroll
    for (int m = 0; m < KK; ++m) o[m] = ti[m];
}

// faithful scrambled-reshape edge value: g in [0, 2*ET)
__device__ __forceinline__ int edge_val(const int* __restrict__ idx, int g) {
    int r = g >> 2;
    int rem = g & 3;
    int b_ = rem >> 1;
    if (rem & 1) return r / KK + b_ * NPB;               // centers (node-major)
    int j = r & (NPB - 1), k = r >> 12;                  // flat (k-major)
    return idx[(size_t)(b_ * NPB + j) * KK + k] + b_ * NPB;
}

// logprobs (direct-diff distance, scrambled gather) + edge arrays
__global__ __launch_bounds__(256) void k_lp_edges(const float* __restrict__ ge,
        const int* __restrict__ idx, const float* __restrict__ tptr,
        float* __restrict__ lp_out, int* __restrict__ e_src, int* __restrict__ e_dst) {
    int q = blockIdx.x * 256 + threadIdx.x;
    if (q >= ET) return;
    float t = clip_exp(tptr);
    int b_ = q / NKR;
    int r  = q - b_ * NKR;
    int fl = idx[(size_t)(b_ * NPB + (r & (NPB - 1))) * KK + (r >> 12)];
    int i  = r / KK;
    const float* ga = ge + (size_t)(b_ * NPB + fl) * DIM;
    const float* gb = ge + (size_t)(b_ * NPB + i) * DIM;
    float s = 0.f;
#pragma unroll 16
    for (int d = 0; d < DIM; ++d) { float df = ga[d] - gb[d]; s = fmaf(df, df, s); }
    lp_out[(size_t)q * 2] = -s * t;
    e_src[q] = edge_val(idx, q);
    e_dst[q] = edge_val(idx, q + ET);
}

__global__ __launch_bounds__(256) void k_init_acc(unsigned* __restrict__ acc) {
    acc[blockIdx.x * 256 + threadIdx.x] = 0x007FFFFFu;   // enc(-inf)
}

// scatter: acc[dst][ch] = max(acc, Q[src][ch])  (1 thread per edge-channel)
__global__ __launch_bounds__(256) void k_scatter(const float* __restrict__ Q,
        const int* __restrict__ esrc, const int* __restrict__ edst,
        unsigned* __restrict__ acc) {
    int idx = blockIdx.x * 256 + threadIdx.x;
    int e = idx >> 6, ch = idx & 63;
    int s = esrc[e], d = edst[e];
    atomicMax(&acc[(size_t)d * DIM + ch], enc_f(Q[(size_t)s * DIM + ch]));
}

// decode: out = relu(max + P) with empty-segment -> 0  (P includes bias)
__global__ __launch_bounds__(256) void k_decode(const unsigned* __restrict__ acc,
        const float* __restrict__ P, float* __restrict__ Y) {
    int v = blockIdx.x * 256 + threadIdx.x;
    float m = dec_f(acc[v]);
    Y[v] = (m == -INFINITY) ? 0.0f : fmaxf(m + P[v], 0.0f);
}

// fc
__global__ __launch_bounds__(256) void k_final(const float* __restrict__ x2,
        const float* __restrict__ Wf1, const float* __restrict__ bf1,
        const float* __restrict__ Wf2, const float* __restrict__ bf2,
        float* __restrict__ out) {
    int i = blockIdx.x * 256 + threadIdx.x;
    const float* xr = x2 + (size_t)i * DIM;
    float xv[DIM];
#pragma unroll
    for (int d = 0; d < DIM; ++d) xv[d] = xr[d];
    float h[32];
#pragma unroll
    for (int c = 0; c < 32; ++c) {
        float a = bf1[c];
#pragma unroll
        for (int d = 0; d < DIM; ++d) a = fmaf(xv[d], Wf1[d * 32 + c], a);
        h[c] = a > 0.f ? a : 0.1f * a;
    }
#pragma unroll
    for (int o8 = 0; o8 < 8; ++o8) {
        float a = bf2[o8];
#pragma unroll
        for (int c = 0; c < 32; ++c) a = fmaf(h[c], Wf2[c * 8 + o8], a);
        out[(size_t)i * 8 + o8] = a;
    }
}

extern "C" void kernel_launch(void* const* d_in, const int* in_sizes, int n_in,
                              void* d_out, int out_size, void* d_ws, size_t ws_size,
                              hipStream_t stream) {
    const float* x    = (const float*)d_in[0];
    const float* Wpre = (const float*)d_in[1];
    const float* bpre = (const float*)d_in[2];
    const float* Wd1  = (const float*)d_in[3];
    const float* bd1  = (const float*)d_in[4];
    const float* t1   = (const float*)d_in[5];
    const float* Wc1  = (const float*)d_in[6];
    const float* bc1  = (const float*)d_in[7];
    const float* Wd2  = (const float*)d_in[8];
    const float* bd2  = (const float*)d_in[9];
    const float* t2   = (const float*)d_in[10];
    const float* Wc2  = (const float*)d_in[11];
    const float* bc2  = (const float*)d_in[12];
    const float* Wf1  = (const float*)d_in[13];
    const float* bf1  = (const float*)d_in[14];
    const float* Wf2  = (const float*)d_in[15];
    const float* bf2  = (const float*)d_in[16];

    float* ws = (float*)d_ws;
    float* x0   = ws;
    float* ge1  = x0  + (size_t)NN * DIM;
    float* x1v  = ge1 + (size_t)NN * DIM;
    float* ge2  = x1v + (size_t)NN * DIM;
    float* x2v  = ge2 + (size_t)NN * DIM;
    float* Pb   = x2v + (size_t)NN * DIM;
    float* Qb   = Pb  + (size_t)NN * DIM;
    float* sqv  = Qb  + (size_t)NN * DIM;
    float* pd   = sqv + NN;
    int*   pi   = (int*)(pd + (size_t)BB * SPLITS * NPB * 8);
    int*   c8   = pi + (size_t)BB * SPLITS * NPB * 8;
    int*   idx1 = c8 + (size_t)BB * NPB * 8;
    int*   idx2 = idx1 + (size_t)BB * NPB * KK;
    int*   es1  = idx2 + (size_t)BB * NPB * KK;
    int*   ed1  = es1 + ET;
    int*   es2  = ed1 + ET;
    int*   ed2  = es2 + ET;
    unsigned* accb = (unsigned*)(ed2 + ET);
    unsigned short* geh = (unsigned short*)(accb + (size_t)NN * DIM);
    unsigned short* gel = geh + (size_t)NN * DIM;

    float* outp = (float*)d_out;
    float* lpp  = outp + (size_t)NN * 8;

    dim3 blk(256);
    dim3 kgrid(NPB / 128, BB, SPLITS);

    k_prefc<<<NN / 4, blk, 0, stream>>>(x, Wpre, bpre, x0);
    k_embed<<<NN / 4, blk, 0, stream>>>(x0, nullptr, Wd1, bd1, ge1, sqv, geh, gel);
    k_knn_mfma<<<kgrid, blk, 0, stream>>>(geh, gel, sqv, t1, pd, pi);
    k_knnmerge8<<<(BB * NPB) / 256, blk, 0, stream>>>(pd, pi, c8);
    k_refine<<<(BB * NPB) / 256, blk, 0, stream>>>(ge1, sqv, c8, t1, idx1);
    k_lp_edges<<<ET / 256, blk, 0, stream>>>(ge1, idx1, t1, lpp + 0, es1, ed1);
    k_pq<<<NN / 4, blk, 0, stream>>>(x0, Wc1, bc1, Pb, Qb);
    k_init_acc<<<(NN * DIM) / 256, blk, 0, stream>>>(accb);
    k_scatter<<<(ET * 64) / 256, blk, 0, stream>>>(Qb, es1, ed1, accb);
    k_decode<<<(NN * DIM) / 256, blk, 0, stream>>>(accb, Pb, x1v);

    k_embed<<<NN / 4, blk, 0, stream>>>(ge1, x1v, Wd2, bd2, ge2, sqv, geh, gel);
    k_knn_mfma<<<kgrid, blk, 0, stream>>>(geh, gel, sqv, t2, pd, pi);
    k_knnmerge8<<<(BB * NPB) / 256, blk, 0, stream>>>(pd, pi, c8);
    k_refine<<<(BB * NPB) / 256, blk, 0, stream>>>(ge2, sqv, c8, t2, idx2);
    k_lp_edges<<<ET / 256, blk, 0, stream>>>(ge2, idx2, t2, lpp + 1, es2, ed2);
    k_pq<<<NN / 4, blk, 0, stream>>>(x1v, Wc2, bc2, Pb, Qb);
    k_init_acc<<<(NN * DIM) / 256, blk, 0, stream>>>(accb);
    k_scatter<<<(ET * 64) / 256, blk, 0, stream>>>(Qb, es2, ed2, accb);
    k_decode<<<(NN * DIM) / 256, blk, 0, stream>>>(accb, Pb, x2v);

    k_final<<<NN / 256, blk, 0, stream>>>(x2v, Wf1, bf1, Wf2, bf2, outp);
}

// Round 8
// 344.770 us; speedup vs baseline: 1.6007x; 1.6007x over previous
//
#include <hip/hip_runtime.h>
#include <math.h>

#define NPB 4096
#define BB 2
#define NN (NPB*BB)          // 8192
#define DIM 64
#define KK 5
#define NKR (NPB*KK)         // 20480
#define ET (BB*NKR)          // 40960 edges
#define SPLITS 16
#define RPS (NPB/SPLITS)     // 256 rows per split
#define NT8 (RPS/32)         // 8 mfma row-tiles per split

typedef __attribute__((ext_vector_type(8))) __bf16 bf16x8;
typedef __attribute__((ext_vector_type(16))) float f32x16;
typedef __attribute__((ext_vector_type(4))) unsigned u32x4;

__device__ __forceinline__ float clip_exp(const float* tptr) {
    return expf(fminf(fmaxf(tptr[0], -5.0f), 5.0f));
}

__device__ __forceinline__ unsigned enc_f(float f) {
    unsigned u = __float_as_uint(f);
    return (u & 0x80000000u) ? ~u : (u | 0x80000000u);
}
__device__ __forceinline__ float dec_f(unsigned e) {
    unsigned u = (e & 0x80000000u) ? (e ^ 0x80000000u) : ~e;
    return __uint_as_float(u);
}

// RNE float -> bf16 bits (finite inputs only)
__device__ __forceinline__ unsigned short f2bf(float f) {
    unsigned u = __float_as_uint(f);
    unsigned r = u + 0x7FFFu + ((u >> 16) & 1u);
    return (unsigned short)(r >> 16);
}

// branchless descending insert into top-8 (u32 packed keys; larger = closer)
__device__ __forceinline__ void insD8(unsigned (&d)[8], unsigned v) {
    bool c[8];
#pragma unroll
    for (int m = 0; m < 8; ++m) c[m] = v > d[m];
#pragma unroll
    for (int m = 7; m > 0; --m) d[m] = c[m - 1] ? d[m - 1] : (c[m] ? v : d[m]);
    d[0] = c[0] ? v : d[0];
}

// ascending lexicographic (d, idx) insert for exact re-rank
template<int NK>
__device__ __forceinline__ void insLex(float (&d)[NK], int (&ix)[NK], float dd, int ii) {
    bool c[NK];
#pragma unroll
    for (int m = 0; m < NK; ++m) c[m] = (dd < d[m]) || (dd == d[m] && ii < ix[m]);
    if (c[NK - 1]) {
#pragma unroll
        for (int m = NK - 1; m > 0; --m) {
            d[m]  = c[m - 1] ? d[m - 1]  : (c[m] ? dd : d[m]);
            ix[m] = c[m - 1] ? ix[m - 1] : (c[m] ? ii : ix[m]);
        }
        if (c[0]) { d[0] = dd; ix[0] = ii; }
    }
}

// ---------------- pre_fc
__global__ __launch_bounds__(256) void k_prefc(const float* __restrict__ X,
        const float* __restrict__ W, const float* __restrict__ bias,
        float* __restrict__ Y) {
    int row = blockIdx.x * 4 + (threadIdx.x >> 6);
    int c = threadIdx.x & 63;
    const float* xr = X + (size_t)row * 32;
    float acc = bias[c];
#pragma unroll
    for (int d = 0; d < 32; ++d) acc = fmaf(xr[d], W[d * 64 + c], acc);
    Y[(size_t)row * 64 + c] = acc > 0.f ? acc : 0.1f * acc;
}

// ---------------- embed: Y = X1@W[0:64] (+ X2@W[64:128]) + b
// emits bf16 hi/lo split, row sq-norms, and packed bf16 pair of (-sq/2)
__global__ __launch_bounds__(256) void k_embed(const float* __restrict__ X1,
        const float* __restrict__ X2, const float* __restrict__ W,
        const float* __restrict__ bias, float* __restrict__ Y,
        float* __restrict__ sqout, unsigned short* __restrict__ GH,
        unsigned short* __restrict__ GL, unsigned* __restrict__ SNH) {
    int row = blockIdx.x * 4 + (threadIdx.x >> 6);
    int c = threadIdx.x & 63;
    float acc = bias[c];
    const float* x1r = X1 + (size_t)row * DIM;
#pragma unroll 16
    for (int d = 0; d < DIM; ++d) acc = fmaf(x1r[d], W[d * DIM + c], acc);
    if (X2) {
        const float* x2r = X2 + (size_t)row * DIM;
#pragma unroll 16
        for (int d = 0; d < DIM; ++d) acc = fmaf(x2r[d], W[(DIM + d) * DIM + c], acc);
    }
    size_t idx = (size_t)row * DIM + c;
    Y[idx] = acc;
    unsigned short h = f2bf(acc);
    float hf = __uint_as_float((unsigned)h << 16);
    GH[idx] = h;
    GL[idx] = f2bf(acc - hf);
    float s = acc * acc;
#pragma unroll
    for (int off = 32; off; off >>= 1) s += __shfl_xor(s, off, 64);
    if (c == 0) {
        sqout[row] = s;
        float ns2 = -0.5f * s;
        unsigned short nh = f2bf(ns2);
        float nhf = __uint_as_float((unsigned)nh << 16);
        unsigned short nl = f2bf(ns2 - nhf);
        SNH[row] = (unsigned)nh | ((unsigned)nl << 16);
    }
}

// ---------------- P/Q for linearized EdgeConv
__global__ __launch_bounds__(256) void k_pq(const float* __restrict__ xf,
        const float* __restrict__ W, const float* __restrict__ bias,
        float* __restrict__ P, float* __restrict__ Q) {
    int row = blockIdx.x * 4 + (threadIdx.x >> 6);
    int c = threadIdx.x & 63;
    const float* xr = xf + (size_t)row * DIM;
    float ap = bias[c], aq = 0.f;
#pragma unroll 16
    for (int d = 0; d < DIM; ++d) {
        float xv = xr[d];
        float w1 = W[(DIM + d) * DIM + c];
        aq = fmaf(xv, w1, aq);
        ap = fmaf(xv, W[d * DIM + c] - w1, ap);
    }
    P[(size_t)row * DIM + c] = ap;
    Q[(size_t)row * DIM + c] = aq;
}

// ---------------- knn via MFMA: acc = dot(gi,gj) - si/2 (si folded via extra
// k-step). Key = order-encoded acc with low 12 bits = ~row (stable ties).
// Branchless top-8 per column per split. No sq loads, no shfl, no t.
__global__ __launch_bounds__(256, 4) void k_knn_mfma(
        const unsigned short* __restrict__ GH, const unsigned short* __restrict__ GL,
        const unsigned* __restrict__ SNH,
        unsigned* __restrict__ pk) {
    const int b_ = blockIdx.y, rs = blockIdx.z;
    const int w = threadIdx.x >> 6, lane = threadIdx.x & 63;
    const int half = lane >> 5, l31 = lane & 31;
    const int col = blockIdx.x * 128 + w * 32 + l31;
    const unsigned short* GHb = GH + (size_t)b_ * NPB * DIM;
    const unsigned short* GLb = GL + (size_t)b_ * NPB * DIM;
    const unsigned* SNHb = SNH + (size_t)b_ * NPB;

    // B frags: col = lane&31, k = ks*16 + half*8 + e
    bf16x8 Bh[4], Bl[4];
    {
        const size_t bro = (size_t)col * DIM + half * 8;
#pragma unroll
        for (int ks = 0; ks < 4; ++ks) {
            Bh[ks] = *(const bf16x8*)&GHb[bro + ks * 16];
            Bl[ks] = *(const bf16x8*)&GLb[bro + ks * 16];
        }
    }
    // B-extra: ones at k=0,1 (half 0 only)
    u32x4 bexu = {half ? 0u : 0x3F803F80u, 0u, 0u, 0u};
    bf16x8 Bex = *(bf16x8*)&bexu;

    unsigned t8[8];
#pragma unroll
    for (int m = 0; m < 8; ++m) t8[m] = 0u;

    const int r0 = rs * RPS;
    for (int tb = 0; tb < NT8; ++tb) {
        const int rbase = r0 + tb * 32;
        const size_t aro = (size_t)(rbase + l31) * DIM + half * 8;
        bf16x8 Ah[4], Al[4];
#pragma unroll
        for (int ks = 0; ks < 4; ++ks) {
            Ah[ks] = *(const bf16x8*)&GHb[aro + ks * 16];
            Al[ks] = *(const bf16x8*)&GLb[aro + ks * 16];
        }
        unsigned sn = SNHb[rbase + l31];
        u32x4 aexu = {half ? 0u : sn, 0u, 0u, 0u};
        bf16x8 Aex = *(bf16x8*)&aexu;

        f32x16 acc = {0,0,0,0,0,0,0,0,0,0,0,0,0,0,0,0};
        acc = __builtin_amdgcn_mfma_f32_32x32x16_bf16(Aex, Bex, acc, 0, 0, 0);
#pragma unroll
        for (int ks = 0; ks < 4; ++ks) {
            acc = __builtin_amdgcn_mfma_f32_32x32x16_bf16(Ah[ks], Bh[ks], acc, 0, 0, 0);
            acc = __builtin_amdgcn_mfma_f32_32x32x16_bf16(Ah[ks], Bl[ks], acc, 0, 0, 0);
            acc = __builtin_amdgcn_mfma_f32_32x32x16_bf16(Al[ks], Bh[ks], acc, 0, 0, 0);
        }
        // C: col=lane&31, row_in_tile = (reg&3)+8*(reg>>2)+4*half
#pragma unroll
        for (int reg = 0; reg < 16; ++reg) {
            const int rit = (reg & 3) + 8 * (reg >> 2) + 4 * half;
            const int row = rbase + rit;
            unsigned u = __float_as_uint(acc[reg]);
            unsigned e = u ^ ((unsigned)((int)u >> 31) | 0x80000000u);
            unsigned p = (e & 0xFFFFF000u) | ((unsigned)(~row) & 0xFFFu);
            insD8(t8, p);
        }
    }
    // merge the two halves (same col, disjoint rows)
    {
        unsigned o[8];
#pragma unroll
        for (int m = 0; m < 8; ++m)
            o[m] = (unsigned)__shfl_xor((int)t8[m], 32, 64);
#pragma unroll
        for (int m = 0; m < 8; ++m) insD8(t8, o[m]);
    }
    if (half == 0) {
        size_t base = (((size_t)(b_ * SPLITS + rs)) * NPB + col) * 8;
#pragma unroll
        for (int m = 0; m < 8; ++m) pk[base + m] = t8[m];
    }
}

// ---------------- select: merge SPLITS top-8 lists, exact fp32 re-rank -> top-5
__global__ __launch_bounds__(256, 2) void k_select(const float* __restrict__ ge,
        const float* __restrict__ sq, const unsigned* __restrict__ pk,
        int* __restrict__ idxout) {
    int q = blockIdx.x * 256 + threadIdx.x;   // over BB*NPB
    int b_ = q >> 12, j = q & (NPB - 1);
    unsigned t8[8];
#pragma unroll
    for (int m = 0; m < 8; ++m) t8[m] = 0u;
    for (int rs = 0; rs < SPLITS; ++rs) {
        const unsigned* src = pk + (((size_t)(b_ * SPLITS + rs)) * NPB + j) * 8;
#pragma unroll
        for (int m = 0; m < 8; ++m) insD8(t8, src[m]);
    }
    const float* geb = ge + (size_t)b_ * NPB * DIM;
    const float* sqb = sq + (size_t)b_ * NPB;
    float4 gjv[16];
#pragma unroll
    for (int d4 = 0; d4 < 16; ++d4)
        gjv[d4] = *(const float4*)&geb[(size_t)j * DIM + d4 * 4];
    float sjv = sqb[j];
    float bd[KK]; int bi[KK];
#pragma unroll
    for (int m = 0; m < KK; ++m) { bd[m] = INFINITY; bi[m] = 0x7FFFFFFF; }
#pragma unroll
    for (int m = 0; m < 8; ++m) {
        int i = (int)((~t8[m]) & 0xFFFu);
        const float* gi = geb + (size_t)i * DIM;
        float dot = 0.f;
#pragma unroll
        for (int d4 = 0; d4 < 16; ++d4) {
            float4 g = *(const float4*)&gi[d4 * 4];
            dot = fmaf(g.x, gjv[d4].x, dot);
            dot = fmaf(g.y, gjv[d4].y, dot);
            dot = fmaf(g.z, gjv[d4].z, dot);
            dot = fmaf(g.w, gjv[d4].w, dot);
        }
        float md = fmaxf(sqb[i] + sjv - 2.0f * dot, 0.0f);
        insLex<KK>(bd, bi, md, i);
    }
    int* o = idxout + (size_t)q * KK;
#pragma unroll
    for (int m = 0; m < KK; ++m) o[m] = bi[m];
}

// faithful scrambled-reshape edge value: g in [0, 2*ET)
__device__ __forceinline__ int edge_val(const int* __restrict__ idx, int g) {
    int r = g >> 2;
    int rem = g & 3;
    int b_ = rem >> 1;
    if (rem & 1) return r / KK + b_ * NPB;               // centers (node-major)
    int j = r & (NPB - 1), k = r >> 12;                  // flat (k-major)
    return idx[(size_t)(b_ * NPB + j) * KK + k] + b_ * NPB;
}

// logprobs + edge arrays
__global__ __launch_bounds__(256) void k_lp_edges(const float* __restrict__ ge,
        const int* __restrict__ idx, const float* __restrict__ tptr,
        float* __restrict__ lp_out, int* __restrict__ e_src, int* __restrict__ e_dst) {
    int q = blockIdx.x * 256 + threadIdx.x;
    if (q >= ET) return;
    float t = clip_exp(tptr);
    int b_ = q / NKR;
    int r  = q - b_ * NKR;
    int fl = idx[(size_t)(b_ * NPB + (r & (NPB - 1))) * KK + (r >> 12)];
    int i  = r / KK;
    const float* ga = ge + (size_t)(b_ * NPB + fl) * DIM;
    const float* gb = ge + (size_t)(b_ * NPB + i) * DIM;
    float s = 0.f;
#pragma unroll 16
    for (int d = 0; d < DIM; ++d) { float df = ga[d] - gb[d]; s = fmaf(df, df, s); }
    lp_out[(size_t)q * 2] = -s * t;
    e_src[q] = edge_val(idx, q);
    e_dst[q] = edge_val(idx, q + ET);
}

__global__ __launch_bounds__(256) void k_init_acc(unsigned* __restrict__ acc) {
    acc[blockIdx.x * 256 + threadIdx.x] = 0x007FFFFFu;   // enc(-inf)
}

// scatter: acc[dst][ch] = max(acc, Q[src][ch])
__global__ __launch_bounds__(256) void k_scatter(const float* __restrict__ Q,
        const int* __restrict__ esrc, const int* __restrict__ edst,
        unsigned* __restrict__ acc) {
    int idx = blockIdx.x * 256 + threadIdx.x;
    int e = idx >> 6, ch = idx & 63;
    int s = esrc[e], d = edst[e];
    atomicMax(&acc[(size_t)d * DIM + ch], enc_f(Q[(size_t)s * DIM + ch]));
}

// decode: out = relu(max + P) with empty-segment -> 0
__global__ __launch_bounds__(256) void k_decode(const unsigned* __restrict__ acc,
        const float* __restrict__ P, float* __restrict__ Y) {
    int v = blockIdx.x * 256 + threadIdx.x;
    float m = dec_f(acc[v]);
    Y[v] = (m == -INFINITY) ? 0.0f : fmaxf(m + P[v], 0.0f);
}

// fc
__global__ __launch_bounds__(256) void k_final(const float* __restrict__ x2,
        const float* __restrict__ Wf1, const float* __restrict__ bf1,
        const float* __restrict__ Wf2, const float* __restrict__ bf2,
        float* __restrict__ out) {
    int i = blockIdx.x * 256 + threadIdx.x;
    const float* xr = x2 + (size_t)i * DIM;
    float xv[DIM];
#pragma unroll
    for (int d = 0; d < DIM; ++d) xv[d] = xr[d];
    float h[32];
#pragma unroll
    for (int c = 0; c < 32; ++c) {
        float a = bf1[c];
#pragma unroll
        for (int d = 0; d < DIM; ++d) a = fmaf(xv[d], Wf1[d * 32 + c], a);
        h[c] = a > 0.f ? a : 0.1f * a;
    }
#pragma unroll
    for (int o8 = 0; o8 < 8; ++o8) {
        float a = bf2[o8];
#pragma unroll
        for (int c = 0; c < 32; ++c) a = fmaf(h[c], Wf2[c * 8 + o8], a);
        out[(size_t)i * 8 + o8] = a;
    }
}

extern "C" void kernel_launch(void* const* d_in, const int* in_sizes, int n_in,
                              void* d_out, int out_size, void* d_ws, size_t ws_size,
                              hipStream_t stream) {
    const float* x    = (const float*)d_in[0];
    const float* Wpre = (const float*)d_in[1];
    const float* bpre = (const float*)d_in[2];
    const float* Wd1  = (const float*)d_in[3];
    const float* bd1  = (const float*)d_in[4];
    const float* t1   = (const float*)d_in[5];
    const float* Wc1  = (const float*)d_in[6];
    const float* bc1  = (const float*)d_in[7];
    const float* Wd2  = (const float*)d_in[8];
    const float* bd2  = (const float*)d_in[9];
    const float* t2   = (const float*)d_in[10];
    const float* Wc2  = (const float*)d_in[11];
    const float* bc2  = (const float*)d_in[12];
    const float* Wf1  = (const float*)d_in[13];
    const float* bf1  = (const float*)d_in[14];
    const float* Wf2  = (const float*)d_in[15];
    const float* bf2  = (const float*)d_in[16];

    float* ws = (float*)d_ws;
    float* x0   = ws;
    float* ge1  = x0  + (size_t)NN * DIM;
    float* x1v  = ge1 + (size_t)NN * DIM;
    float* ge2  = x1v + (size_t)NN * DIM;
    float* x2v  = ge2 + (size_t)NN * DIM;
    float* Pb   = x2v + (size_t)NN * DIM;
    float* Qb   = Pb  + (size_t)NN * DIM;
    float* sqv  = Qb  + (size_t)NN * DIM;
    unsigned* pk = (unsigned*)(sqv + NN);
    int*   idx1 = (int*)(pk + (size_t)BB * SPLITS * NPB * 8);
    int*   idx2 = idx1 + (size_t)BB * NPB * KK;
    int*   es1  = idx2 + (size_t)BB * NPB * KK;
    int*   ed1  = es1 + ET;
    int*   es2  = ed1 + ET;
    int*   ed2  = es2 + ET;
    unsigned* accb = (unsigned*)(ed2 + ET);
    unsigned short* geh = (unsigned short*)(accb + (size_t)NN * DIM);
    unsigned short* gel = geh + (size_t)NN * DIM;
    unsigned* snh = (unsigned*)(gel + (size_t)NN * DIM);

    float* outp = (float*)d_out;
    float* lpp  = outp + (size_t)NN * 8;

    dim3 blk(256);
    dim3 kgrid(NPB / 128, BB, SPLITS);

    k_prefc<<<NN / 4, blk, 0, stream>>>(x, Wpre, bpre, x0);
    k_embed<<<NN / 4, blk, 0, stream>>>(x0, nullptr, Wd1, bd1, ge1, sqv, geh, gel, snh);
    k_knn_mfma<<<kgrid, blk, 0, stream>>>(geh, gel, snh, pk);
    k_select<<<(BB * NPB) / 256, blk, 0, stream>>>(ge1, sqv, pk, idx1);
    k_lp_edges<<<ET / 256, blk, 0, stream>>>(ge1, idx1, t1, lpp + 0, es1, ed1);
    k_pq<<<NN / 4, blk, 0, stream>>>(x0, Wc1, bc1, Pb, Qb);
    k_init_acc<<<(NN * DIM) / 256, blk, 0, stream>>>(accb);
    k_scatter<<<(ET * 64) / 256, blk, 0, stream>>>(Qb, es1, ed1, accb);
    k_decode<<<(NN * DIM) / 256, blk, 0, stream>>>(accb, Pb, x1v);

    k_embed<<<NN / 4, blk, 0, stream>>>(ge1, x1v, Wd2, bd2, ge2, sqv, geh, gel, snh);
    k_knn_mfma<<<kgrid, blk, 0, stream>>>(geh, gel, snh, pk);
    k_select<<<(BB * NPB) / 256, blk, 0, stream>>>(ge2, sqv, pk, idx2);
    k_lp_edges<<<ET / 256, blk, 0, stream>>>(ge2, idx2, t2, lpp + 1, es2, ed2);
    k_pq<<<NN / 4, blk, 0, stream>>>(x1v, Wc2, bc2, Pb, Qb);
    k_init_acc<<<(NN * DIM) / 256, blk, 0, stream>>>(accb);
    k_scatter<<<(ET * 64) / 256, blk, 0, stream>>>(Qb, es2, ed2, accb);
    k_decode<<<(NN * DIM) / 256, blk, 0, stream>>>(accb, Pb, x2v);

    k_final<<<NN / 256, blk, 0, stream>>>(x2v, Wf1, bf1, Wf2, bf2, outp);
}